// Round 6
// baseline (505.006 us; speedup 1.0000x reference)
//
#include <hip/hip_runtime.h>
#include <math.h>

#define S 2048
#define DD 2048
#define NH 16
#define DH 128
#define DHID 128
#define DKER 64
#define EPSF 1e-6f

typedef __attribute__((ext_vector_type(8))) short bf16x8;
typedef __attribute__((ext_vector_type(4))) float f32x4;

__device__ __forceinline__ float gelu_f(float x) {
    return 0.5f * x * (1.0f + erff(x * 0.7071067811865475f));
}

__device__ __forceinline__ ushort f2b(float x) {
    uint32_t u = __float_as_uint(x);
    uint32_t r = (u + 0x7FFFu + ((u >> 16) & 1u)) >> 16;
    return (ushort)r;
}

__device__ __forceinline__ bf16x8 pack8(float4 a, float4 b) {
    bf16x8 r;
    r[0] = (short)f2b(a.x); r[1] = (short)f2b(a.y);
    r[2] = (short)f2b(a.z); r[3] = (short)f2b(a.w);
    r[4] = (short)f2b(b.x); r[5] = (short)f2b(b.y);
    r[6] = (short)f2b(b.z); r[7] = (short)f2b(b.w);
    return r;
}

// merge LR score (bf16, A-layout) with sparse exp(w) under mask bits
__device__ __forceinline__ bf16x8 merge8(bf16x8 ps, uint mb, f32x4 wa, f32x4 wb) {
    float w[8] = {wa[0], wa[1], wa[2], wa[3], wb[0], wb[1], wb[2], wb[3]};
    bf16x8 r;
    #pragma unroll
    for (int j = 0; j < 8; ++j) {
        float sv = __uint_as_float(((uint)(ushort)ps[j]) << 16);
        float p = ((mb >> j) & 1) ? (sv + EPSF) : __expf(w[j]);
        r[j] = (short)f2b(p);
    }
    return r;
}

// direct-to-LDS DMA (no dest VGPR, not sinkable by the scheduler)
__device__ __forceinline__ void gl16(const void* g, void* l) {
    __builtin_amdgcn_global_load_lds((const __attribute__((address_space(1))) uint*)g,
                                     (__attribute__((address_space(3))) uint*)l, 16, 0, 0);
}
__device__ __forceinline__ void gl4(const void* g, void* l) {
    __builtin_amdgcn_global_load_lds((const __attribute__((address_space(1))) uint*)g,
                                     (__attribute__((address_space(3))) uint*)l, 4, 0, 0);
}

// ---- weight prep: transpose+convert to bf16 [out_dim][in_dim] ----
__global__ __launch_bounds__(256) void k_wprep(const float* __restrict__ wq1,
                                               const float* __restrict__ wk1,
                                               const float* __restrict__ wq2,
                                               const float* __restrict__ wk2,
                                               const float* __restrict__ ik,
                                               ushort* __restrict__ w1qt,
                                               ushort* __restrict__ w1kt,
                                               ushort* __restrict__ w2qt,
                                               ushort* __restrict__ w2kt,
                                               ushort* __restrict__ ikt) {
    const int h = blockIdx.x, m = blockIdx.y, tid = threadIdx.x;
    const float* src; ushort* dst; int D;
    if (m == 0)      { src = wq1 + h * 16384; dst = w1qt + h * 16384; D = 128; }
    else if (m == 1) { src = wk1 + h * 16384; dst = w1kt + h * 16384; D = 128; }
    else if (m == 2) { src = wq2 + h * 8192;  dst = w2qt + h * 8192;  D = 128; }
    else if (m == 3) { src = wk2 + h * 8192;  dst = w2kt + h * 8192;  D = 128; }
    else             { src = ik  + h * 4096;  dst = ikt  + h * 4096;  D = 64;  }
    const int E = (m == 0 || m == 1) ? 128 : 64;
    const int dsh = (D == 128) ? 7 : 6;
    const int n = E * D;
    for (int idx = tid; idx < n; idx += 256) {
        int e = idx >> dsh, d = idx & (D - 1);
        dst[idx] = f2b(src[d * E + e]);
    }
}

// ---- fused MLP paths: z=0 -> Q2abs, z=1 -> K3abs ----
__global__ __launch_bounds__(256) void k_fused(const float* __restrict__ Xq,
                                               const float* __restrict__ Xk,
                                               const ushort* __restrict__ w1qt,
                                               const ushort* __restrict__ w1kt,
                                               const ushort* __restrict__ w2qt,
                                               const ushort* __restrict__ w2kt,
                                               const ushort* __restrict__ ikt,
                                               const float* __restrict__ sD,
                                               const float* __restrict__ sD2,
                                               ushort* __restrict__ Q2,
                                               ushort* __restrict__ K3) {
    const int h = blockIdx.y;
    const int s0 = blockIdx.x * 64;
    const int z = blockIdx.z;
    const int tid = threadIdx.x;
    const int wv = tid >> 6, lane = tid & 63;
    const int ln = lane & 15, quad = lane >> 4;
    __shared__ ushort Y1s[64][136];   // 272B row ≡ 4 dw mod 32 banks
    __shared__ ushort K2s[64][72];

    const float* X = z ? Xk : Xq;
    const ushort* w1t = z ? w1kt : w1qt;
    const ushort* w2t = z ? w2kt : w2qt;

    // A1: X rows (fp32 -> bf16), direct from global
    const float* Xr = X + (size_t)(s0 + wv * 16 + ln) * DD + h * DH;
    bf16x8 a1[4];
    #pragma unroll
    for (int ks = 0; ks < 4; ++ks)
        a1[ks] = pack8(*(const float4*)(Xr + ks * 32 + quad * 8),
                       *(const float4*)(Xr + ks * 32 + quad * 8 + 4));

    // mlp1: 64x128 @ 128x128
    const ushort* W1h = w1t + (size_t)h * DH * DHID;
    f32x4 c1[8];
    #pragma unroll
    for (int n = 0; n < 8; ++n) c1[n] = (f32x4){0.f, 0.f, 0.f, 0.f};
    #pragma unroll
    for (int ks = 0; ks < 4; ++ks) {
        bf16x8 bb[8];
        #pragma unroll
        for (int n = 0; n < 8; ++n)
            bb[n] = *(const bf16x8*)(W1h + (size_t)(n * 16 + ln) * DHID +
                                     ks * 32 + quad * 8);
        #pragma unroll
        for (int n = 0; n < 8; ++n)
            c1[n] = __builtin_amdgcn_mfma_f32_16x16x32_bf16(a1[ks], bb[n], c1[n], 0, 0, 0);
    }
    #pragma unroll
    for (int n = 0; n < 8; ++n)
        #pragma unroll
        for (int r = 0; r < 4; ++r)
            Y1s[wv * 16 + quad * 4 + r][n * 16 + ln] = f2b(gelu_f(c1[n][r]));

    // mlp2: 64x128 @ 128x64  (rows are wave-private; same-wave DS ordering)
    bf16x8 a2[4];
    #pragma unroll
    for (int ks = 0; ks < 4; ++ks)
        a2[ks] = *(const bf16x8*)&Y1s[wv * 16 + ln][ks * 32 + quad * 8];
    const ushort* W2h = w2t + (size_t)h * DKER * DHID;
    f32x4 c2[4];
    #pragma unroll
    for (int n = 0; n < 4; ++n) c2[n] = (f32x4){0.f, 0.f, 0.f, 0.f};
    #pragma unroll
    for (int ks = 0; ks < 4; ++ks) {
        bf16x8 bb[4];
        #pragma unroll
        for (int n = 0; n < 4; ++n)
            bb[n] = *(const bf16x8*)(W2h + (size_t)(n * 16 + ln) * DHID +
                                     ks * 32 + quad * 8);
        #pragma unroll
        for (int n = 0; n < 4; ++n)
            c2[n] = __builtin_amdgcn_mfma_f32_16x16x32_bf16(a2[ks], bb[n], c2[n], 0, 0, 0);
    }

    if (z == 0) {
        #pragma unroll
        for (int n = 0; n < 4; ++n)
            #pragma unroll
            for (int r = 0; r < 4; ++r)
                Q2[((size_t)h * S + s0 + wv * 16 + quad * 4 + r) * DKER + n * 16 + ln] =
                    f2b(fabsf(gelu_f(c2[n][r])));
        return;
    }

    // k path: k2 = |sD| * gelu; k3 = |k2 + (k2 @ Ik) * sD2|
    float k2v[4][4];
    float sdv[4], sd2v[4];
    #pragma unroll
    for (int n = 0; n < 4; ++n) {
        sdv[n]  = fabsf(sD[h * DKER + n * 16 + ln]);
        sd2v[n] = sD2[h * DKER + n * 16 + ln];
    }
    #pragma unroll
    for (int n = 0; n < 4; ++n)
        #pragma unroll
        for (int r = 0; r < 4; ++r) {
            k2v[n][r] = sdv[n] * gelu_f(c2[n][r]);
            K2s[wv * 16 + quad * 4 + r][n * 16 + ln] = f2b(k2v[n][r]);
        }
    bf16x8 a3[2];
    #pragma unroll
    for (int ks = 0; ks < 2; ++ks)
        a3[ks] = *(const bf16x8*)&K2s[wv * 16 + ln][ks * 32 + quad * 8];
    const ushort* Ikh = ikt + (size_t)h * DKER * DKER;
    f32x4 c3[4];
    #pragma unroll
    for (int n = 0; n < 4; ++n) c3[n] = (f32x4){0.f, 0.f, 0.f, 0.f};
    #pragma unroll
    for (int ks = 0; ks < 2; ++ks) {
        bf16x8 bb[4];
        #pragma unroll
        for (int n = 0; n < 4; ++n)
            bb[n] = *(const bf16x8*)(Ikh + (size_t)(n * 16 + ln) * DKER +
                                     ks * 32 + quad * 8);
        #pragma unroll
        for (int n = 0; n < 4; ++n)
            c3[n] = __builtin_amdgcn_mfma_f32_16x16x32_bf16(a3[ks], bb[n], c3[n], 0, 0, 0);
    }
    #pragma unroll
    for (int n = 0; n < 4; ++n)
        #pragma unroll
        for (int r = 0; r < 4; ++r)
            K3[((size_t)h * S + s0 + wv * 16 + quad * 4 + r) * DKER + n * 16 + ln] =
                f2b(fabsf(k2v[n][r] + c3[n][r] * sd2v[n]));
}

// ---- Vt[h][c][t] = bf16( V[t][h*128+c] ) ----
__global__ __launch_bounds__(256) void k_vt(const float* __restrict__ V,
                                            ushort* __restrict__ Vt) {
    const int h = blockIdx.y;
    const int t0 = blockIdx.x * 64;
    const int tid = threadIdx.x;
    __shared__ ushort Ls[128][72];
    #pragma unroll
    for (int it = 0; it < 8; ++it) {
        int idx = it * 256 + tid;
        int r = idx >> 5, c4 = idx & 31;
        float4 v = *(const float4*)(V + (size_t)(t0 + r) * DD + h * DH + c4 * 4);
        Ls[c4 * 4 + 0][r] = f2b(v.x);
        Ls[c4 * 4 + 1][r] = f2b(v.y);
        Ls[c4 * 4 + 2][r] = f2b(v.z);
        Ls[c4 * 4 + 3][r] = f2b(v.w);
    }
    __syncthreads();
    #pragma unroll
    for (int it = 0; it < 4; ++it) {
        int idx = it * 256 + tid;
        int row = idx >> 3, cc = idx & 7;
        *(bf16x8*)(Vt + ((size_t)h * DH + row) * S + t0 + cc * 8) =
            *(const bf16x8*)(&Ls[row][cc * 8]);
    }
}

// ---- pack mask bits ----
__global__ __launch_bounds__(256) void k_mpack(const int* __restrict__ mask,
                                               uint* __restrict__ pm) {
    const int gw = blockIdx.x * 4 + (threadIdx.x >> 6);
    const int lane = threadIdx.x & 63;
    const int row = gw >> 5;
    const int w64 = gw & 31;
    int mv = mask[(size_t)row * S + w64 * 64 + lane];
    unsigned long long b = __ballot(mv != 0);
    if (lane == 0)  pm[row * 64 + w64 * 2]     = (uint)b;
    if (lane == 32) pm[row * 64 + w64 * 2 + 1] = (uint)(b >> 32);
}

// ---- fused attention, global_load_lds + counted-vmcnt pipeline ----
// All per-tile streams (K3, Vt, Wsp fp32, mask words) are DMA'd direct to LDS
// (no dest VGPRs -> scheduler cannot serialize them). Double-buffered 32-t
// tiles; per wave exactly 5 DMA issues/tile (wave0: 6 incl. mask) so the
// steady-state wait is s_waitcnt vmcnt(5/6) - the NEXT tile's loads stay in
// flight across the barrier. LDS layouts are XOR-swizzled via pre-swizzled
// GLOBAL source addresses (linear DMA dest) + the same XOR on ds_read.
__global__ __launch_bounds__(256, 2) void k_attn(const ushort* __restrict__ Q2,
                                                 const ushort* __restrict__ K3,
                                                 const ushort* __restrict__ Vt,
                                                 const uint* __restrict__ pm,
                                                 const float* __restrict__ Wsp,
                                                 const float* __restrict__ lse,
                                                 float* __restrict__ out) {
    const int bid = blockIdx.x;
    const int id = (bid & 7) * 64 + (bid >> 3);   // XCD-contiguous remap (512 = 8*64)
    const int h = id >> 5;
    const int s0 = (id & 31) * 64;
    const int tid = threadIdx.x;
    const int wv = tid >> 6, lane = tid & 63;
    const int ln = lane & 15, quad = lane >> 4;

    __shared__ ushort Ks[2][32][64];   // [buf][t][feat]  128B rows, swz chunk^= (t&7)
    __shared__ ushort Vs[2][128][32];  // [buf][d][t]      64B rows, swz chunk^= (d&3)
    __shared__ float  Ws[2][64][32];   // [buf][q][t]     128B rows, swz chunk^= (q&7)
    __shared__ uint   Ms[2][64];       // [buf][q] mask word for this tile
    __shared__ ushort Ps[4][16][40];   // wave-private P transpose

    const ushort* K3h = K3 + (size_t)h * S * DKER;
    const ushort* Vth = Vt + (size_t)h * DH * S;
    const float*  Wh  = Wsp + (size_t)h * S * S;
    const int srow_q = s0 + wv * 16 + quad * 4;   // C/D-layout base row
    const int arow   = s0 + wv * 16 + ln;         // A-layout row

    // per-lane pre-swizzled staging source coords (row&mask ≡ f(lane) on all)
    const int kR = wv * 8 + (lane >> 3);
    const int kC = ((lane & 7) ^ ((lane >> 3) & 7)) * 8;    // ushort offset
    const int vR = wv * 32 + (lane >> 2);                   // +16 for issue 1
    const int vC = ((lane & 3) ^ ((lane >> 2) & 3)) * 8;    // ushort offset
    const int wR = wv * 16 + (lane >> 3);                   // +8 for issue 1
    const int wC = ((lane & 7) ^ ((lane >> 3) & 7)) * 4;    // float offset

    // loop-invariant Q2 A-fragments (retire before the loop's counted waits)
    bf16x8 aq[2];
    #pragma unroll
    for (int ks = 0; ks < 2; ++ks)
        aq[ks] = *(const bf16x8*)(Q2 + ((size_t)h * S + arow) * DKER +
                                  ks * 32 + quad * 8);

    f32x4 O[8];
    #pragma unroll
    for (int v = 0; v < 8; ++v) O[v] = (f32x4){0.f, 0.f, 0.f, 0.f};
    float rs[4] = {0.f, 0.f, 0.f, 0.f};

#define STAGE(T, B) do {                                                           \
    const int t0_ = (T) * 32;                                                      \
    gl16(K3h + (size_t)(t0_ + kR) * DKER + kC, &Ks[B][wv * 8][0]);                 \
    gl16(Vth + (size_t)vR * S + t0_ + vC, &Vs[B][wv * 32][0]);                     \
    gl16(Vth + (size_t)(vR + 16) * S + t0_ + vC, &Vs[B][wv * 32 + 16][0]);         \
    gl16(Wh + (size_t)(s0 + wR) * S + t0_ + wC, &Ws[B][wv * 16][0]);               \
    gl16(Wh + (size_t)(s0 + wR + 8) * S + t0_ + wC, &Ws[B][wv * 16 + 8][0]);       \
    if (wv == 0) gl4(pm + (size_t)(s0 + lane) * 64 + (T), &Ms[B][0]);              \
} while (0)

#define COMPUTE(B) do {                                                            \
    f32x4 sc[2];                                                                   \
    sc[0] = (f32x4){0.f, 0.f, 0.f, 0.f};                                           \
    sc[1] = (f32x4){0.f, 0.f, 0.f, 0.f};                                           \
    _Pragma("unroll") for (int ks_ = 0; ks_ < 2; ++ks_)                            \
    _Pragma("unroll") for (int n_ = 0; n_ < 2; ++n_) {                             \
        bf16x8 bf = *(const bf16x8*)&Ks[B][n_ * 16 + ln]                           \
                                       [((ks_ * 4 + quad) ^ (ln & 7)) * 8];        \
        sc[n_] = __builtin_amdgcn_mfma_f32_16x16x32_bf16(aq[ks_], bf, sc[n_],      \
                                                         0, 0, 0);                  \
    }                                                                              \
    uint mwq[4];                                                                   \
    _Pragma("unroll") for (int r_ = 0; r_ < 4; ++r_)                               \
        mwq[r_] = Ms[B][wv * 16 + quad * 4 + r_];                                  \
    _Pragma("unroll") for (int n_ = 0; n_ < 2; ++n_)                               \
    _Pragma("unroll") for (int r_ = 0; r_ < 4; ++r_) {                             \
        int m_ = (mwq[r_] >> (n_ * 16 + ln)) & 1;                                  \
        float s_ = sc[n_][r_];                                                     \
        if (m_) rs[r_] += s_;                                                      \
        Ps[wv][quad * 4 + r_][n_ * 16 + ln] = f2b(s_);                             \
    }                                                                              \
    uint mwa = Ms[B][wv * 16 + ln];                                                \
    bf16x8 ps = *(const bf16x8*)&Ps[wv][ln][quad * 8];                             \
    f32x4 w0 = *(const f32x4*)&Ws[B][wv * 16 + ln][((quad * 2) ^ (ln & 7)) * 4];   \
    f32x4 w1 = *(const f32x4*)&Ws[B][wv * 16 + ln]                                 \
                                 [((quad * 2 + 1) ^ (ln & 7)) * 4];                \
    bf16x8 pa = merge8(ps, mwa >> (quad * 8), w0, w1);                             \
    _Pragma("unroll") for (int v_ = 0; v_ < 8; ++v_) {                             \
        bf16x8 vf = *(const bf16x8*)&Vs[B][v_ * 16 + ln][(quad ^ (ln & 3)) * 8];   \
        O[v_] = __builtin_amdgcn_mfma_f32_16x16x32_bf16(pa, vf, O[v_], 0, 0, 0);   \
    }                                                                              \
} while (0)

    STAGE(0, 0);
    for (int t = 0; t < 63; ++t) {
        const int bc = t & 1, bn = bc ^ 1;
        STAGE(t + 1, bn);                       // next tile in flight across barrier
        if (wv == 0) asm volatile("s_waitcnt vmcnt(6)" ::: "memory");
        else         asm volatile("s_waitcnt vmcnt(5)" ::: "memory");
        __builtin_amdgcn_s_barrier();
        asm volatile("" ::: "memory");
        COMPUTE(bc);
        asm volatile("" ::: "memory");
        __builtin_amdgcn_s_barrier();           // all waves done reading buf bc
        asm volatile("" ::: "memory");
    }
    asm volatile("s_waitcnt vmcnt(0)" ::: "memory");
    __builtin_amdgcn_s_barrier();
    asm volatile("" ::: "memory");
    COMPUTE(1);                                 // tile 63
#undef STAGE
#undef COMPUTE

    // rowsum across the 16 lanes sharing each C/D row
    #pragma unroll
    for (int r = 0; r < 4; ++r) {
        float v = rs[r];
        v += __shfl_xor(v, 1); v += __shfl_xor(v, 2);
        v += __shfl_xor(v, 4); v += __shfl_xor(v, 8);
        rs[r] = v;
    }
    float idv[4];
    #pragma unroll
    for (int r = 0; r < 4; ++r)
        idv[r] = 1.f / (rs[r] + EPSF + expf(lse[(size_t)h * S + srow_q + r]));
    #pragma unroll
    for (int v = 0; v < 8; ++v)
        #pragma unroll
        for (int r = 0; r < 4; ++r)
            out[(size_t)(srow_q + r) * DD + h * DH + v * 16 + ln] = O[v][r] * idv[r];
}

extern "C" void kernel_launch(void* const* d_in, const int* in_sizes, int n_in,
                              void* d_out, int out_size, void* d_ws, size_t ws_size,
                              hipStream_t stream) {
    const float* q   = (const float*)d_in[0];
    const float* k   = (const float*)d_in[1];
    const float* v   = (const float*)d_in[2];
    const int*   msk = (const int*)d_in[3];
    const float* lse = (const float*)d_in[4];
    const float* spw = (const float*)d_in[5];
    const float* wq1 = (const float*)d_in[6];
    const float* wk1 = (const float*)d_in[7];
    const float* wq2 = (const float*)d_in[8];
    const float* wk2 = (const float*)d_in[9];
    const float* ik  = (const float*)d_in[10];
    const float* sD  = (const float*)d_in[11];
    const float* sD2 = (const float*)d_in[12];
    float* out = (float*)d_out;

    ushort* q2b  = (ushort*)d_ws;                          // 16*2048*64
    ushort* k3b  = q2b + (size_t)NH * S * DKER;            // 16*2048*64
    ushort* vt   = k3b + (size_t)NH * S * DKER;            // 16*128*2048
    uint*   pm   = (uint*)(vt + (size_t)NH * DH * S);      // 2048*64
    ushort* w1qt = (ushort*)(pm + (size_t)S * 64);         // 16*128*128
    ushort* w1kt = w1qt + (size_t)NH * DH * DHID;
    ushort* w2qt = w1kt + (size_t)NH * DH * DHID;          // 16*64*128
    ushort* w2kt = w2qt + (size_t)NH * DKER * DHID;
    ushort* ikt  = w2kt + (size_t)NH * DKER * DHID;        // 16*64*64

    dim3 g(S / 64, NH), b(256);
    k_wprep<<<dim3(NH, 5), b, 0, stream>>>(wq1, wk1, wq2, wk2, ik,
                                           w1qt, w1kt, w2qt, w2kt, ikt);
    k_mpack<<<dim3(S * 32 / 4), b, 0, stream>>>(msk, pm);
    k_vt<<<g, b, 0, stream>>>(v, vt);
    k_fused<<<dim3(S / 64, NH, 2), b, 0, stream>>>(q, k, w1qt, w1kt, w2qt, w2kt,
                                                   ikt, sD, sD2, q2b, k3b);
    k_attn<<<dim3(512), b, 0, stream>>>(q2b, k3b, vt, pm, spw, lse, out);
}